// Round 10
// baseline (173.024 us; speedup 1.0000x reference)
//
#include <hip/hip_runtime.h>

// SpMM out[b,r,:] += v[e] * feat[b, c(e), :], COO, N=50000, NNZ=1.6M, B=2, D=128 fp32.
// Tier A (5 launches):
//   1. init_fixed : bbase[b]=gcur[b]=b*BCAP
//   2. partpack   : fused partition (LDS-staged, u32 key {row8|col16} + u16 bf16 val,
//                   coalesced run writes into per-bucket regions) + feat pack
//                   f32[B][n][D] -> bf16[n][B][D]
//   3. bucket_sort: per-bucket 256-row counting sort -> cv u32 {bf16val|col}
//   4+5. seg reduce SPLIT BY BATCH: per dispatch the gather working set is the
//        batch's 12.8MB half-table (vs 25.6) -> fewer L2 capacity misses on the
//        XCD<->L3 fill path (the measured seg bottleneck, ~350MB @ ~3.3TB/s).
//        Wave = 2 edges (half-wave each, 8B/lane), shfl_xor(32) merge, lanes
//        0-31 store the fp32 row. NT cv loads, NT out stores.
// Tier C: compact layout via hist+scan. Fallback: atomic scatter.

#define FEAT_D 128
#define BATCH 2
#define RB_SHIFT 8
#define NB_MAX 256
#define BCAP 10240
#define PART_E 8192
#define PART_T 512
#define PACK_BLOCKS 1024

typedef int   iv4 __attribute__((ext_vector_type(4)));
typedef float fv4 __attribute__((ext_vector_type(4)));
typedef unsigned uv2 __attribute__((ext_vector_type(2)));

__device__ inline unsigned short f32_to_bf16_rne(float f) {
  unsigned u = __float_as_uint(f);
  unsigned r = u + 0x7fffu + ((u >> 16) & 1u);
  return (unsigned short)(r >> 16);
}

__device__ inline uv2 tbl_load(const unsigned short* pbase, unsigned p) {
  // packed row stride = BATCH*FEAT_D = 256 shorts; col in low 16 bits of p
  return *reinterpret_cast<const uv2*>(pbase + ((size_t)(p & 0xffffu) << 8));
}
__device__ inline void fma_edge(fv4& acc, unsigned p, uv2 w) {
  const float v = __uint_as_float(p & 0xffff0000u);  // bf16 val in high 16
  acc.x += v * __uint_as_float(w.x << 16);
  acc.y += v * __uint_as_float(w.x & 0xffff0000u);
  acc.z += v * __uint_as_float(w.y << 16);
  acc.w += v * __uint_as_float(w.y & 0xffff0000u);
}

// ---------- 1a. fixed-path init ----------
__global__ void __launch_bounds__(NB_MAX) init_fixed_kernel(
    int* __restrict__ bbase, int* __restrict__ gcur, int nb) {
  const int t = threadIdx.x;
  if (t < nb) {
    bbase[t] = t * BCAP;
    gcur[t] = t * BCAP;
  }
}

// ---------- 1b/1c. compact-path hist + scan ----------
__global__ void __launch_bounds__(256) hist_bucket_kernel(
    const int* __restrict__ rows, int nnz, int* __restrict__ bcnt) {
  __shared__ int h[256];
  h[threadIdx.x] = 0;
  __syncthreads();
  const int n4 = nnz >> 2;
  for (int i = blockIdx.x * blockDim.x + threadIdx.x; i < n4;
       i += gridDim.x * blockDim.x) {
    const iv4 r4 = *(reinterpret_cast<const iv4*>(rows) + i);
    atomicAdd(&h[r4.x >> RB_SHIFT], 1);
    atomicAdd(&h[r4.y >> RB_SHIFT], 1);
    atomicAdd(&h[r4.z >> RB_SHIFT], 1);
    atomicAdd(&h[r4.w >> RB_SHIFT], 1);
  }
  if (blockIdx.x == 0 && threadIdx.x < (nnz & 3))
    atomicAdd(&h[rows[(n4 << 2) + threadIdx.x] >> RB_SHIFT], 1);
  __syncthreads();
  if (h[threadIdx.x]) atomicAdd(&bcnt[threadIdx.x], h[threadIdx.x]);
}

__global__ void __launch_bounds__(256) scan_buckets_kernel(
    const int* __restrict__ bcnt, int nb,
    int* __restrict__ bbase, int* __restrict__ gcur) {
  __shared__ int sc[256];
  const int tid = threadIdx.x;
  const int v = (tid < nb) ? bcnt[tid] : 0;
  sc[tid] = v;
  __syncthreads();
  for (int off = 1; off < 256; off <<= 1) {
    int t = (tid >= off) ? sc[tid - off] : 0;
    __syncthreads();
    sc[tid] += t;
    __syncthreads();
  }
  const int excl = sc[tid] - v;
  if (tid < nb) {
    bbase[tid] = excl;
    gcur[tid] = excl;
  }
}

// ---------- partition body ----------
__device__ inline void partition_body(
    const int* __restrict__ rows, const int* __restrict__ cols,
    const float* __restrict__ vals, int nnz, int nb,
    int* __restrict__ gcur,
    unsigned* __restrict__ cvb_key, unsigned short* __restrict__ cvb_val,
    int blk, int* hist, int* excl, int* cur, int* gdst,
    unsigned* stage_key, unsigned short* stage_val, unsigned char* slotb) {
  const int tid = threadIdx.x;
  const int base = blk * PART_E;
  const int cnt = min(PART_E, nnz - base);

  if (tid < 256) hist[tid] = 0;
  __syncthreads();

  for (int k = tid; k < cnt; k += PART_T)
    atomicAdd(&hist[rows[base + k] >> RB_SHIFT], 1);
  __syncthreads();

  if (tid < 256) excl[tid] = hist[tid];
  __syncthreads();
  for (int off = 1; off < 256; off <<= 1) {
    int v = 0;
    if (tid < 256 && tid >= off) v = excl[tid - off];
    __syncthreads();
    if (tid < 256) excl[tid] += v;
    __syncthreads();
  }
  if (tid < 256) {
    const int e = excl[tid] - hist[tid];
    excl[tid] = e;
    cur[tid] = e;
    int gd = 0;
    if (tid < nb && hist[tid] > 0) {
      const int gb = atomicAdd(&gcur[tid], hist[tid]);
      gd = gb - e;
    }
    gdst[tid] = gd;
  }
  __syncthreads();

  for (int k = tid; k < cnt; k += PART_T) {
    const int e = base + k;
    const int r = rows[e];
    const int c = __builtin_nontemporal_load(&cols[e]);
    const float v = __builtin_nontemporal_load(&vals[e]);
    const int b = r >> RB_SHIFT;
    const int pos = atomicAdd(&cur[b], 1);
    stage_key[pos] = (unsigned)(((r & 255) << 16) | c);
    stage_val[pos] = f32_to_bf16_rne(v);
    slotb[pos] = (unsigned char)b;
  }
  __syncthreads();

  for (int i = tid; i < cnt; i += PART_T) {
    const int b = slotb[i];
    const int idx = gdst[b] + i;
    cvb_key[idx] = stage_key[i];
    cvb_val[idx] = stage_val[i];
  }
}

// ---------- 2a. standalone partition ----------
__global__ void __launch_bounds__(PART_T) partition_kernel(
    const int* __restrict__ rows, const int* __restrict__ cols,
    const float* __restrict__ vals, int nnz, int nb,
    int* __restrict__ gcur,
    unsigned* __restrict__ cvb_key, unsigned short* __restrict__ cvb_val) {
  __shared__ int hist[256];
  __shared__ int excl[256];
  __shared__ int cur[256];
  __shared__ int gdst[256];
  __shared__ unsigned stage_key[PART_E];
  __shared__ unsigned short stage_val[PART_E];
  __shared__ unsigned char slotb[PART_E];
  partition_body(rows, cols, vals, nnz, nb, gcur, cvb_key, cvb_val, blockIdx.x,
                 hist, excl, cur, gdst, stage_key, stage_val, slotb);
}

// ---------- 2b. fused partition + pack (tier A) ----------
__global__ void __launch_bounds__(PART_T) partpack_kernel(
    const int* __restrict__ rows, const int* __restrict__ cols,
    const float* __restrict__ vals, int nnz, int nb,
    int* __restrict__ gcur,
    unsigned* __restrict__ cvb_key, unsigned short* __restrict__ cvb_val,
    const float* __restrict__ feat, unsigned short* __restrict__ packed,
    int n, int part_blocks) {
  __shared__ int hist[256];
  __shared__ int excl[256];
  __shared__ int cur[256];
  __shared__ int gdst[256];
  __shared__ unsigned stage_key[PART_E];
  __shared__ unsigned short stage_val[PART_E];
  __shared__ unsigned char slotb[PART_E];

  if ((int)blockIdx.x < part_blocks) {
    partition_body(rows, cols, vals, nnz, nb, gcur, cvb_key, cvb_val, blockIdx.x,
                   hist, excl, cur, gdst, stage_key, stage_val, slotb);
  } else {
    const int pb = blockIdx.x - part_blocks;
    const int npb = gridDim.x - part_blocks;
    const int total = n * (BATCH * FEAT_D / 4);
    for (int q = pb * PART_T + threadIdx.x; q < total; q += npb * PART_T) {
      const int r = q >> 6;
      const int rem = q & 63;
      const int b = rem >> 5;
      const int d4 = rem & 31;
      const fv4 x = __builtin_nontemporal_load(reinterpret_cast<const fv4*>(
          feat + ((size_t)b * n + r) * FEAT_D + (size_t)d4 * 4));
      unsigned a0 = (unsigned)f32_to_bf16_rne(x.x) | ((unsigned)f32_to_bf16_rne(x.y) << 16);
      unsigned a1 = (unsigned)f32_to_bf16_rne(x.z) | ((unsigned)f32_to_bf16_rne(x.w) << 16);
      uv2 o; o.x = a0; o.y = a1;
      *reinterpret_cast<uv2*>(packed + (size_t)q * 4) = o;
    }
  }
}

// ---------- 3. per-bucket counting sort by row ----------
__global__ void __launch_bounds__(256) bucket_sort_kernel(
    const unsigned* __restrict__ cvb_key, const unsigned short* __restrict__ cvb_val,
    const int* __restrict__ bbase, const int* __restrict__ gcur,
    int* __restrict__ offsets, int* __restrict__ rowend,
    unsigned* __restrict__ cv, int n) {
  __shared__ int h[256];
  __shared__ int sc[256];
  __shared__ int cur[256];
  const int tid = threadIdx.x;
  const int b = blockIdx.x;
  const int start = bbase[b];
  const int end = gcur[b];

  h[tid] = 0;
  __syncthreads();
  for (int i = start + tid; i < end; i += 256)
    atomicAdd(&h[cvb_key[i] >> 16], 1);
  __syncthreads();
  sc[tid] = h[tid];
  __syncthreads();
  for (int off = 1; off < 256; off <<= 1) {
    int t = (tid >= off) ? sc[tid - off] : 0;
    __syncthreads();
    sc[tid] += t;
    __syncthreads();
  }
  const int excl = sc[tid] - h[tid];
  const int row = (b << RB_SHIFT) + tid;
  if (row < n) {
    offsets[row] = start + excl;
    rowend[row] = start + excl + h[tid];
  }
  cur[tid] = start + excl;
  __syncthreads();
  for (int i = start + tid; i < end; i += 256) {
    const unsigned key = cvb_key[i];
    const unsigned val = (unsigned)cvb_val[i];
    const int pos = atomicAdd(&cur[key >> 16], 1);
    cv[pos] = (val << 16) | (key & 0xffffu);
  }
}

// ---------- 4. standalone pack (tier C) ----------
__global__ void __launch_bounds__(256) pack_kernel(
    const float* __restrict__ feat, unsigned short* __restrict__ packed, int n) {
  const int q = blockIdx.x * blockDim.x + threadIdx.x;
  const int total = n * (BATCH * FEAT_D / 4);
  if (q >= total) return;
  const int r = q >> 6;
  const int rem = q & 63;
  const int b = rem >> 5;
  const int d4 = rem & 31;
  const fv4 x = __builtin_nontemporal_load(reinterpret_cast<const fv4*>(
      feat + ((size_t)b * n + r) * FEAT_D + (size_t)d4 * 4));
  unsigned a0 = (unsigned)f32_to_bf16_rne(x.x) | ((unsigned)f32_to_bf16_rne(x.y) << 16);
  unsigned a1 = (unsigned)f32_to_bf16_rne(x.z) | ((unsigned)f32_to_bf16_rne(x.w) << 16);
  uv2 o; o.x = a0; o.y = a1;
  *reinterpret_cast<uv2*>(packed + (size_t)q * 4) = o;
}

// ---------- 5. segment reduce, one batch per dispatch ----------
// Wave handles 2 edges per step: lanes 0-31 edge i, lanes 32-63 edge i+1,
// each lane 8B of the batch's 256B row; shfl_xor(32) merges, lanes 0-31 store.
__global__ void __launch_bounds__(256) spmm_seg_split_kernel(
    const int* __restrict__ offsets, const int* __restrict__ rowend,
    const unsigned* __restrict__ cv,
    const unsigned short* __restrict__ packed,
    float* __restrict__ out, int n, int batch) {
  const int wid = (int)((blockIdx.x * (unsigned)blockDim.x + threadIdx.x) >> 6);
  if (wid >= n) return;
  const int lane = threadIdx.x & 63;
  const int half = lane >> 5;
  const int l32 = lane & 31;

  int start = __builtin_amdgcn_readfirstlane(offsets[wid]);
  int end = __builtin_amdgcn_readfirstlane(rowend[wid]);

  // this lane's 8B slot within the batch's 256B half-row
  const unsigned short* pbase = packed + (size_t)batch * FEAT_D + (size_t)l32 * 4;

  fv4 acc; acc.x = 0.f; acc.y = 0.f; acc.z = 0.f; acc.w = 0.f;
  int i = start;
  for (; i + 8 <= end; i += 8) {
    const unsigned p0 = __builtin_nontemporal_load(&cv[i + 0 + half]);
    const unsigned p1 = __builtin_nontemporal_load(&cv[i + 2 + half]);
    const unsigned p2 = __builtin_nontemporal_load(&cv[i + 4 + half]);
    const unsigned p3 = __builtin_nontemporal_load(&cv[i + 6 + half]);
    const uv2 w0 = tbl_load(pbase, p0);
    const uv2 w1 = tbl_load(pbase, p1);
    const uv2 w2 = tbl_load(pbase, p2);
    const uv2 w3 = tbl_load(pbase, p3);
    fma_edge(acc, p0, w0);
    fma_edge(acc, p1, w1);
    fma_edge(acc, p2, w2);
    fma_edge(acc, p3, w3);
  }
  for (; i < end; i += 2) {
    const int idx = i + half;
    unsigned p = 0;
    if (idx < end) p = __builtin_nontemporal_load(&cv[idx]);
    // p==0 -> val bf16 0.0 -> contributes nothing (col-0 gather harmless)
    fma_edge(acc, p, tbl_load(pbase, p));
  }

  // merge the two half-wave partial sums (same d-range in lane l and l+32)
  acc.x += __shfl_xor(acc.x, 32);
  acc.y += __shfl_xor(acc.y, 32);
  acc.z += __shfl_xor(acc.z, 32);
  acc.w += __shfl_xor(acc.w, 32);

  if (half == 0) {
    const size_t bs = (size_t)n * FEAT_D;
    float* dst = out + (size_t)batch * bs + (size_t)wid * FEAT_D + (size_t)l32 * 4;
    __builtin_nontemporal_store(acc, reinterpret_cast<fv4*>(dst));
  }
}

// ---------- last-resort fallback: atomic scatter ----------
__global__ void __launch_bounds__(256) spmm_atomic_kernel(
    const int* __restrict__ indices, const float* __restrict__ values,
    const float* __restrict__ feat, float* __restrict__ out, int nnz, int n) {
  const long long gid = (long long)blockIdx.x * blockDim.x + threadIdx.x;
  const int lane = (int)(gid & 31);
  const long long e = gid >> 5;
  if (e >= nnz) return;
  const int r = indices[e];
  const int c = indices[(long long)nnz + e];
  const float v = values[e];
  const size_t bs = (size_t)n * FEAT_D;
  for (int b = 0; b < BATCH; ++b) {
    const float4 a = *(reinterpret_cast<const float4*>(feat + b * bs + (size_t)c * FEAT_D) + lane);
    float* dst = out + b * bs + (size_t)r * FEAT_D + (size_t)lane * 4;
    atomicAdd(dst + 0, v * a.x);
    atomicAdd(dst + 1, v * a.y);
    atomicAdd(dst + 2, v * a.z);
    atomicAdd(dst + 3, v * a.w);
  }
}

static inline size_t align256(size_t x) { return (x + 255) & ~(size_t)255; }

extern "C" void kernel_launch(void* const* d_in, const int* in_sizes, int n_in,
                              void* d_out, int out_size, void* d_ws, size_t ws_size,
                              hipStream_t stream) {
  const int* indices = (const int*)d_in[0];
  const float* values = (const float*)d_in[1];
  const float* feat = (const float*)d_in[3];
  float* out = (float*)d_out;

  const int nnz = in_sizes[1];
  const int n = out_size / (BATCH * FEAT_D);
  const int nb = (n + 255) >> RB_SHIFT;

  const int* rows = indices;
  const int* cols = indices + nnz;

  size_t off_offsets = 0;
  size_t off_rowend = off_offsets + (size_t)n * 4;
  size_t off_bcnt = off_rowend + (size_t)n * 4;
  size_t off_bbase = off_bcnt + (size_t)NB_MAX * 4;
  size_t off_gcur = off_bbase + (size_t)NB_MAX * 4;
  size_t off_cv = align256(off_gcur + (size_t)NB_MAX * 4);

  const size_t packed_bytes = (size_t)n * BATCH * FEAT_D * 2;
  const size_t entA = (size_t)nb * BCAP;
  const size_t entC = (size_t)nnz;

  const size_t offA_key = align256(off_cv + entA * 4);
  const size_t offA_val = align256(offA_key + entA * 4);
  const size_t offA_packed = align256(offA_val + entA * 2);
  const size_t needA = offA_packed + packed_bytes;
  const size_t offC_key = align256(off_cv + entC * 4);
  const size_t offC_val = align256(offC_key + entC * 4);
  const size_t offC_packed = align256(offC_val + entC * 2);
  const size_t needC = offC_packed + packed_bytes;

  const int avg = nnz / (nb > 0 ? nb : 1);
  const bool cap_ok = (avg + avg / 8 + 256) < BCAP;
  const bool shape_ok = (n <= (NB_MAX << RB_SHIFT)) && (nb <= NB_MAX) && (n <= 65536);

  if (!shape_ok || ws_size < needC) {
    hipMemsetAsync(d_out, 0, (size_t)out_size * sizeof(float), stream);
    const long long total_threads = (long long)nnz * 32;
    const unsigned grid = (unsigned)((total_threads + 255) / 256);
    spmm_atomic_kernel<<<grid, 256, 0, stream>>>(indices, values, feat, out, nnz, n);
    return;
  }

  char* ws = (char*)d_ws;
  int* offsets = (int*)(ws + off_offsets);
  int* rowend = (int*)(ws + off_rowend);
  int* bcnt = (int*)(ws + off_bcnt);
  int* bbase = (int*)(ws + off_bbase);
  int* gcur = (int*)(ws + off_gcur);
  unsigned* cv = (unsigned*)(ws + off_cv);

  const int part_blocks = (nnz + PART_E - 1) / PART_E;
  const int pack_total = n * (BATCH * FEAT_D / 4);
  const unsigned seg_grid = (unsigned)(((long long)n * 64 + 255) / 256);

  if (cap_ok && ws_size >= needA) {
    // ---- tier A ----
    unsigned* cvb_key = (unsigned*)(ws + offA_key);
    unsigned short* cvb_val = (unsigned short*)(ws + offA_val);
    unsigned short* packed = (unsigned short*)(ws + offA_packed);
    init_fixed_kernel<<<1, NB_MAX, 0, stream>>>(bbase, gcur, nb);
    partpack_kernel<<<part_blocks + PACK_BLOCKS, PART_T, 0, stream>>>(
        rows, cols, values, nnz, nb, gcur, cvb_key, cvb_val, feat, packed, n, part_blocks);
    bucket_sort_kernel<<<nb, 256, 0, stream>>>(cvb_key, cvb_val, bbase, gcur,
                                               offsets, rowend, cv, n);
    spmm_seg_split_kernel<<<seg_grid, 256, 0, stream>>>(offsets, rowend, cv, packed, out, n, 0);
    spmm_seg_split_kernel<<<seg_grid, 256, 0, stream>>>(offsets, rowend, cv, packed, out, n, 1);
  } else {
    // ---- tier C ----
    unsigned* cvb_key = (unsigned*)(ws + offC_key);
    unsigned short* cvb_val = (unsigned short*)(ws + offC_val);
    unsigned short* packed = (unsigned short*)(ws + offC_packed);
    hipMemsetAsync(bcnt, 0, (size_t)NB_MAX * 4, stream);
    hist_bucket_kernel<<<512, 256, 0, stream>>>(rows, nnz, bcnt);
    scan_buckets_kernel<<<1, 256, 0, stream>>>(bcnt, nb, bbase, gcur);
    partition_kernel<<<part_blocks, PART_T, 0, stream>>>(rows, cols, values, nnz, nb,
                                                         gcur, cvb_key, cvb_val);
    bucket_sort_kernel<<<nb, 256, 0, stream>>>(cvb_key, cvb_val, bbase, gcur,
                                               offsets, rowend, cv, n);
    pack_kernel<<<(pack_total + 255) / 256, 256, 0, stream>>>(feat, packed, n);
    spmm_seg_split_kernel<<<seg_grid, 256, 0, stream>>>(offsets, rowend, cv, packed, out, n, 0);
    spmm_seg_split_kernel<<<seg_grid, 256, 0, stream>>>(offsets, rowend, cv, packed, out, n, 1);
  }
}

// Round 11
// 155.240 us; speedup vs baseline: 1.1146x; 1.1146x over previous
//
#include <hip/hip_runtime.h>

// SpMM out[b,r,:] += v[e] * feat[b, c(e), :], COO, N=50000, NNZ=1.6M, B=2, D=128 fp32.
// Tier A (4 launches):
//   1. init_fixed : bbase[b]=gcur[b]=b*BCAP
//   2. partpack   : fused partition (LDS-staged, u32 key {row8|col16} + u16 bf16 val)
//                   + feat pack f32[B][n][D] -> bf16[n][B][D]
//   3. bucket_sort: LDS-staged per-bucket counting sort (one global read pass,
//                   LDS->LDS scatter, coalesced cv writeback) -> cv u32 {bf16val|col}
//   4. seg reduce : one wave per row, 8-edge unroll, 512B gathers (both batches),
//                   fp32 acc, NT cv loads, NT out stores.
// Seg is pinned at ~107us / ~346MB FETCH: compulsory 8-XCD x 25.6MB table fill
// through the L2-miss path at ~3.3TB/s (six optimization attempts all null).
// Tier C: compact layout via hist+scan. Fallback: atomic scatter.

#define FEAT_D 128
#define BATCH 2
#define RB_SHIFT 8
#define NB_MAX 256
#define BCAP 10240
#define PART_E 8192
#define PART_T 512
#define PACK_BLOCKS 1024

typedef int   iv4 __attribute__((ext_vector_type(4)));
typedef float fv4 __attribute__((ext_vector_type(4)));
typedef unsigned uv2 __attribute__((ext_vector_type(2)));

__device__ inline unsigned short f32_to_bf16_rne(float f) {
  unsigned u = __float_as_uint(f);
  unsigned r = u + 0x7fffu + ((u >> 16) & 1u);
  return (unsigned short)(r >> 16);
}

__device__ inline uv2 tbl_load(const unsigned short* pbase, unsigned p) {
  // packed row stride = BATCH*FEAT_D = 256 shorts; col in low 16 bits of p
  return *reinterpret_cast<const uv2*>(pbase + ((size_t)(p & 0xffffu) << 8));
}
__device__ inline void fma_edge(fv4& acc, unsigned p, uv2 w) {
  const float v = __uint_as_float(p & 0xffff0000u);  // bf16 val in high 16
  acc.x += v * __uint_as_float(w.x << 16);
  acc.y += v * __uint_as_float(w.x & 0xffff0000u);
  acc.z += v * __uint_as_float(w.y << 16);
  acc.w += v * __uint_as_float(w.y & 0xffff0000u);
}

// ---------- 1a. fixed-path init ----------
__global__ void __launch_bounds__(NB_MAX) init_fixed_kernel(
    int* __restrict__ bbase, int* __restrict__ gcur, int nb) {
  const int t = threadIdx.x;
  if (t < nb) {
    bbase[t] = t * BCAP;
    gcur[t] = t * BCAP;
  }
}

// ---------- 1b/1c. compact-path hist + scan ----------
__global__ void __launch_bounds__(256) hist_bucket_kernel(
    const int* __restrict__ rows, int nnz, int* __restrict__ bcnt) {
  __shared__ int h[256];
  h[threadIdx.x] = 0;
  __syncthreads();
  const int n4 = nnz >> 2;
  for (int i = blockIdx.x * blockDim.x + threadIdx.x; i < n4;
       i += gridDim.x * blockDim.x) {
    const iv4 r4 = *(reinterpret_cast<const iv4*>(rows) + i);
    atomicAdd(&h[r4.x >> RB_SHIFT], 1);
    atomicAdd(&h[r4.y >> RB_SHIFT], 1);
    atomicAdd(&h[r4.z >> RB_SHIFT], 1);
    atomicAdd(&h[r4.w >> RB_SHIFT], 1);
  }
  if (blockIdx.x == 0 && threadIdx.x < (nnz & 3))
    atomicAdd(&h[rows[(n4 << 2) + threadIdx.x] >> RB_SHIFT], 1);
  __syncthreads();
  if (h[threadIdx.x]) atomicAdd(&bcnt[threadIdx.x], h[threadIdx.x]);
}

__global__ void __launch_bounds__(256) scan_buckets_kernel(
    const int* __restrict__ bcnt, int nb,
    int* __restrict__ bbase, int* __restrict__ gcur) {
  __shared__ int sc[256];
  const int tid = threadIdx.x;
  const int v = (tid < nb) ? bcnt[tid] : 0;
  sc[tid] = v;
  __syncthreads();
  for (int off = 1; off < 256; off <<= 1) {
    int t = (tid >= off) ? sc[tid - off] : 0;
    __syncthreads();
    sc[tid] += t;
    __syncthreads();
  }
  const int excl = sc[tid] - v;
  if (tid < nb) {
    bbase[tid] = excl;
    gcur[tid] = excl;
  }
}

// ---------- partition body ----------
__device__ inline void partition_body(
    const int* __restrict__ rows, const int* __restrict__ cols,
    const float* __restrict__ vals, int nnz, int nb,
    int* __restrict__ gcur,
    unsigned* __restrict__ cvb_key, unsigned short* __restrict__ cvb_val,
    int blk, int* hist, int* excl, int* cur, int* gdst,
    unsigned* stage_key, unsigned short* stage_val, unsigned char* slotb) {
  const int tid = threadIdx.x;
  const int base = blk * PART_E;
  const int cnt = min(PART_E, nnz - base);

  if (tid < 256) hist[tid] = 0;
  __syncthreads();

  for (int k = tid; k < cnt; k += PART_T)
    atomicAdd(&hist[rows[base + k] >> RB_SHIFT], 1);
  __syncthreads();

  if (tid < 256) excl[tid] = hist[tid];
  __syncthreads();
  for (int off = 1; off < 256; off <<= 1) {
    int v = 0;
    if (tid < 256 && tid >= off) v = excl[tid - off];
    __syncthreads();
    if (tid < 256) excl[tid] += v;
    __syncthreads();
  }
  if (tid < 256) {
    const int e = excl[tid] - hist[tid];
    excl[tid] = e;
    cur[tid] = e;
    int gd = 0;
    if (tid < nb && hist[tid] > 0) {
      const int gb = atomicAdd(&gcur[tid], hist[tid]);
      gd = gb - e;
    }
    gdst[tid] = gd;
  }
  __syncthreads();

  for (int k = tid; k < cnt; k += PART_T) {
    const int e = base + k;
    const int r = rows[e];
    const int c = __builtin_nontemporal_load(&cols[e]);
    const float v = __builtin_nontemporal_load(&vals[e]);
    const int b = r >> RB_SHIFT;
    const int pos = atomicAdd(&cur[b], 1);
    stage_key[pos] = (unsigned)(((r & 255) << 16) | c);
    stage_val[pos] = f32_to_bf16_rne(v);
    slotb[pos] = (unsigned char)b;
  }
  __syncthreads();

  for (int i = tid; i < cnt; i += PART_T) {
    const int b = slotb[i];
    const int idx = gdst[b] + i;
    cvb_key[idx] = stage_key[i];
    cvb_val[idx] = stage_val[i];
  }
}

// ---------- 2a. standalone partition (tier C) ----------
__global__ void __launch_bounds__(PART_T) partition_kernel(
    const int* __restrict__ rows, const int* __restrict__ cols,
    const float* __restrict__ vals, int nnz, int nb,
    int* __restrict__ gcur,
    unsigned* __restrict__ cvb_key, unsigned short* __restrict__ cvb_val) {
  __shared__ int hist[256];
  __shared__ int excl[256];
  __shared__ int cur[256];
  __shared__ int gdst[256];
  __shared__ unsigned stage_key[PART_E];
  __shared__ unsigned short stage_val[PART_E];
  __shared__ unsigned char slotb[PART_E];
  partition_body(rows, cols, vals, nnz, nb, gcur, cvb_key, cvb_val, blockIdx.x,
                 hist, excl, cur, gdst, stage_key, stage_val, slotb);
}

// ---------- 2b. fused partition + pack (tier A) ----------
__global__ void __launch_bounds__(PART_T) partpack_kernel(
    const int* __restrict__ rows, const int* __restrict__ cols,
    const float* __restrict__ vals, int nnz, int nb,
    int* __restrict__ gcur,
    unsigned* __restrict__ cvb_key, unsigned short* __restrict__ cvb_val,
    const float* __restrict__ feat, unsigned short* __restrict__ packed,
    int n, int part_blocks) {
  __shared__ int hist[256];
  __shared__ int excl[256];
  __shared__ int cur[256];
  __shared__ int gdst[256];
  __shared__ unsigned stage_key[PART_E];
  __shared__ unsigned short stage_val[PART_E];
  __shared__ unsigned char slotb[PART_E];

  if ((int)blockIdx.x < part_blocks) {
    partition_body(rows, cols, vals, nnz, nb, gcur, cvb_key, cvb_val, blockIdx.x,
                   hist, excl, cur, gdst, stage_key, stage_val, slotb);
  } else {
    const int pb = blockIdx.x - part_blocks;
    const int npb = gridDim.x - part_blocks;
    const int total = n * (BATCH * FEAT_D / 4);
    for (int q = pb * PART_T + threadIdx.x; q < total; q += npb * PART_T) {
      const int r = q >> 6;
      const int rem = q & 63;
      const int b = rem >> 5;
      const int d4 = rem & 31;
      const fv4 x = __builtin_nontemporal_load(reinterpret_cast<const fv4*>(
          feat + ((size_t)b * n + r) * FEAT_D + (size_t)d4 * 4));
      unsigned a0 = (unsigned)f32_to_bf16_rne(x.x) | ((unsigned)f32_to_bf16_rne(x.y) << 16);
      unsigned a1 = (unsigned)f32_to_bf16_rne(x.z) | ((unsigned)f32_to_bf16_rne(x.w) << 16);
      uv2 o; o.x = a0; o.y = a1;
      *reinterpret_cast<uv2*>(packed + (size_t)q * 4) = o;
    }
  }
}

// ---------- 3. per-bucket counting sort, LDS-staged ----------
__global__ void __launch_bounds__(256) bucket_sort_kernel(
    const unsigned* __restrict__ cvb_key, const unsigned short* __restrict__ cvb_val,
    const int* __restrict__ bbase, const int* __restrict__ gcur,
    int* __restrict__ offsets, int* __restrict__ rowend,
    unsigned* __restrict__ cv, int n) {
  __shared__ unsigned skey[BCAP];       // 40 KB
  __shared__ unsigned short sval[BCAP]; // 20 KB
  __shared__ unsigned sdst[BCAP];       // 40 KB
  __shared__ int h[256];
  __shared__ int sc[256];
  __shared__ int cur[256];
  const int tid = threadIdx.x;
  const int b = blockIdx.x;
  const int start = bbase[b];
  const int end = gcur[b];
  const int cnt = end - start;

  if (cnt <= BCAP) {
    // one coalesced read pass into LDS
    for (int i = tid; i < cnt; i += 256) {
      skey[i] = cvb_key[start + i];
      sval[i] = cvb_val[start + i];
    }
    h[tid] = 0;
    __syncthreads();
    for (int i = tid; i < cnt; i += 256) atomicAdd(&h[skey[i] >> 16], 1);
    __syncthreads();
    sc[tid] = h[tid];
    __syncthreads();
    for (int off = 1; off < 256; off <<= 1) {
      int t = (tid >= off) ? sc[tid - off] : 0;
      __syncthreads();
      sc[tid] += t;
      __syncthreads();
    }
    const int excl = sc[tid] - h[tid];
    const int row = (b << RB_SHIFT) + tid;
    if (row < n) {
      offsets[row] = start + excl;
      rowend[row] = start + excl + h[tid];
    }
    cur[tid] = excl;
    __syncthreads();
    // LDS -> LDS scatter into row-sorted order
    for (int i = tid; i < cnt; i += 256) {
      const unsigned key = skey[i];
      const int pos = atomicAdd(&cur[key >> 16], 1);
      sdst[pos] = ((unsigned)sval[i] << 16) | (key & 0xffffu);
    }
    __syncthreads();
    // coalesced writeback
    for (int i = tid; i < cnt; i += 256) cv[start + i] = sdst[i];
  } else {
    // global 2-pass fallback (oversized bucket)
    h[tid] = 0;
    __syncthreads();
    for (int i = start + tid; i < end; i += 256)
      atomicAdd(&h[cvb_key[i] >> 16], 1);
    __syncthreads();
    sc[tid] = h[tid];
    __syncthreads();
    for (int off = 1; off < 256; off <<= 1) {
      int t = (tid >= off) ? sc[tid - off] : 0;
      __syncthreads();
      sc[tid] += t;
      __syncthreads();
    }
    const int excl = sc[tid] - h[tid];
    const int row = (b << RB_SHIFT) + tid;
    if (row < n) {
      offsets[row] = start + excl;
      rowend[row] = start + excl + h[tid];
    }
    cur[tid] = start + excl;
    __syncthreads();
    for (int i = start + tid; i < end; i += 256) {
      const unsigned key = cvb_key[i];
      const unsigned val = (unsigned)cvb_val[i];
      const int pos = atomicAdd(&cur[key >> 16], 1);
      cv[pos] = (val << 16) | (key & 0xffffu);
    }
  }
}

// ---------- 4. standalone pack (tier C) ----------
__global__ void __launch_bounds__(256) pack_kernel(
    const float* __restrict__ feat, unsigned short* __restrict__ packed, int n) {
  const int q = blockIdx.x * blockDim.x + threadIdx.x;
  const int total = n * (BATCH * FEAT_D / 4);
  if (q >= total) return;
  const int r = q >> 6;
  const int rem = q & 63;
  const int b = rem >> 5;
  const int d4 = rem & 31;
  const fv4 x = __builtin_nontemporal_load(reinterpret_cast<const fv4*>(
      feat + ((size_t)b * n + r) * FEAT_D + (size_t)d4 * 4));
  unsigned a0 = (unsigned)f32_to_bf16_rne(x.x) | ((unsigned)f32_to_bf16_rne(x.y) << 16);
  unsigned a1 = (unsigned)f32_to_bf16_rne(x.z) | ((unsigned)f32_to_bf16_rne(x.w) << 16);
  uv2 o; o.x = a0; o.y = a1;
  *reinterpret_cast<uv2*>(packed + (size_t)q * 4) = o;
}

// ---------- 5. segment reduce (unsplit; the measured-floor config) ----------
__global__ void __launch_bounds__(256) spmm_seg_bf16_kernel(
    const int* __restrict__ offsets, const int* __restrict__ rowend,
    const unsigned* __restrict__ cv,
    const unsigned short* __restrict__ packed,
    float* __restrict__ out, int n) {
  const int wid = (int)((blockIdx.x * (unsigned)blockDim.x + threadIdx.x) >> 6);
  if (wid >= n) return;
  const int lane = threadIdx.x & 63;

  int start = __builtin_amdgcn_readfirstlane(offsets[wid]);
  int end = __builtin_amdgcn_readfirstlane(rowend[wid]);

  const unsigned short* pbase = packed + (size_t)lane * 4;

  fv4 acc; acc.x = 0.f; acc.y = 0.f; acc.z = 0.f; acc.w = 0.f;
  int i = start;
  for (; i + 8 <= end; i += 8) {
    const unsigned p0 = __builtin_nontemporal_load(&cv[i + 0]);
    const unsigned p1 = __builtin_nontemporal_load(&cv[i + 1]);
    const unsigned p2 = __builtin_nontemporal_load(&cv[i + 2]);
    const unsigned p3 = __builtin_nontemporal_load(&cv[i + 3]);
    const unsigned p4 = __builtin_nontemporal_load(&cv[i + 4]);
    const unsigned p5 = __builtin_nontemporal_load(&cv[i + 5]);
    const unsigned p6 = __builtin_nontemporal_load(&cv[i + 6]);
    const unsigned p7 = __builtin_nontemporal_load(&cv[i + 7]);
    const uv2 w0 = tbl_load(pbase, p0);
    const uv2 w1 = tbl_load(pbase, p1);
    const uv2 w2 = tbl_load(pbase, p2);
    const uv2 w3 = tbl_load(pbase, p3);
    const uv2 w4 = tbl_load(pbase, p4);
    const uv2 w5 = tbl_load(pbase, p5);
    const uv2 w6 = tbl_load(pbase, p6);
    const uv2 w7 = tbl_load(pbase, p7);
    fma_edge(acc, p0, w0);
    fma_edge(acc, p1, w1);
    fma_edge(acc, p2, w2);
    fma_edge(acc, p3, w3);
    fma_edge(acc, p4, w4);
    fma_edge(acc, p5, w5);
    fma_edge(acc, p6, w6);
    fma_edge(acc, p7, w7);
  }
  for (; i < end; ++i) {
    const unsigned p = __builtin_nontemporal_load(&cv[i]);
    fma_edge(acc, p, tbl_load(pbase, p));
  }

  const int half = lane >> 5;
  const int l32 = lane & 31;
  const size_t bs = (size_t)n * FEAT_D;
  float* dst = out + (size_t)half * bs + (size_t)wid * FEAT_D + (size_t)l32 * 4;
  __builtin_nontemporal_store(acc, reinterpret_cast<fv4*>(dst));
}

// ---------- last-resort fallback: atomic scatter ----------
__global__ void __launch_bounds__(256) spmm_atomic_kernel(
    const int* __restrict__ indices, const float* __restrict__ values,
    const float* __restrict__ feat, float* __restrict__ out, int nnz, int n) {
  const long long gid = (long long)blockIdx.x * blockDim.x + threadIdx.x;
  const int lane = (int)(gid & 31);
  const long long e = gid >> 5;
  if (e >= nnz) return;
  const int r = indices[e];
  const int c = indices[(long long)nnz + e];
  const float v = values[e];
  const size_t bs = (size_t)n * FEAT_D;
  for (int b = 0; b < BATCH; ++b) {
    const float4 a = *(reinterpret_cast<const float4*>(feat + b * bs + (size_t)c * FEAT_D) + lane);
    float* dst = out + b * bs + (size_t)r * FEAT_D + (size_t)lane * 4;
    atomicAdd(dst + 0, v * a.x);
    atomicAdd(dst + 1, v * a.y);
    atomicAdd(dst + 2, v * a.z);
    atomicAdd(dst + 3, v * a.w);
  }
}

static inline size_t align256(size_t x) { return (x + 255) & ~(size_t)255; }

extern "C" void kernel_launch(void* const* d_in, const int* in_sizes, int n_in,
                              void* d_out, int out_size, void* d_ws, size_t ws_size,
                              hipStream_t stream) {
  const int* indices = (const int*)d_in[0];
  const float* values = (const float*)d_in[1];
  const float* feat = (const float*)d_in[3];
  float* out = (float*)d_out;

  const int nnz = in_sizes[1];
  const int n = out_size / (BATCH * FEAT_D);
  const int nb = (n + 255) >> RB_SHIFT;

  const int* rows = indices;
  const int* cols = indices + nnz;

  size_t off_offsets = 0;
  size_t off_rowend = off_offsets + (size_t)n * 4;
  size_t off_bcnt = off_rowend + (size_t)n * 4;
  size_t off_bbase = off_bcnt + (size_t)NB_MAX * 4;
  size_t off_gcur = off_bbase + (size_t)NB_MAX * 4;
  size_t off_cv = align256(off_gcur + (size_t)NB_MAX * 4);

  const size_t packed_bytes = (size_t)n * BATCH * FEAT_D * 2;
  const size_t entA = (size_t)nb * BCAP;
  const size_t entC = (size_t)nnz;

  const size_t offA_key = align256(off_cv + entA * 4);
  const size_t offA_val = align256(offA_key + entA * 4);
  const size_t offA_packed = align256(offA_val + entA * 2);
  const size_t needA = offA_packed + packed_bytes;
  const size_t offC_key = align256(off_cv + entC * 4);
  const size_t offC_val = align256(offC_key + entC * 4);
  const size_t offC_packed = align256(offC_val + entC * 2);
  const size_t needC = offC_packed + packed_bytes;

  const int avg = nnz / (nb > 0 ? nb : 1);
  const bool cap_ok = (avg + avg / 8 + 256) < BCAP;
  const bool shape_ok = (n <= (NB_MAX << RB_SHIFT)) && (nb <= NB_MAX) && (n <= 65536);

  if (!shape_ok || ws_size < needC) {
    hipMemsetAsync(d_out, 0, (size_t)out_size * sizeof(float), stream);
    const long long total_threads = (long long)nnz * 32;
    const unsigned grid = (unsigned)((total_threads + 255) / 256);
    spmm_atomic_kernel<<<grid, 256, 0, stream>>>(indices, values, feat, out, nnz, n);
    return;
  }

  char* ws = (char*)d_ws;
  int* offsets = (int*)(ws + off_offsets);
  int* rowend = (int*)(ws + off_rowend);
  int* bcnt = (int*)(ws + off_bcnt);
  int* bbase = (int*)(ws + off_bbase);
  int* gcur = (int*)(ws + off_gcur);
  unsigned* cv = (unsigned*)(ws + off_cv);

  const int part_blocks = (nnz + PART_E - 1) / PART_E;
  const int pack_total = n * (BATCH * FEAT_D / 4);
  const unsigned seg_grid = (unsigned)(((long long)n * 64 + 255) / 256);

  if (cap_ok && ws_size >= needA) {
    // ---- tier A: 4 launches ----
    unsigned* cvb_key = (unsigned*)(ws + offA_key);
    unsigned short* cvb_val = (unsigned short*)(ws + offA_val);
    unsigned short* packed = (unsigned short*)(ws + offA_packed);
    init_fixed_kernel<<<1, NB_MAX, 0, stream>>>(bbase, gcur, nb);
    partpack_kernel<<<part_blocks + PACK_BLOCKS, PART_T, 0, stream>>>(
        rows, cols, values, nnz, nb, gcur, cvb_key, cvb_val, feat, packed, n, part_blocks);
    bucket_sort_kernel<<<nb, 256, 0, stream>>>(cvb_key, cvb_val, bbase, gcur,
                                               offsets, rowend, cv, n);
    spmm_seg_bf16_kernel<<<seg_grid, 256, 0, stream>>>(offsets, rowend, cv, packed, out, n);
  } else {
    // ---- tier C: compact layout via hist+scan ----
    unsigned* cvb_key = (unsigned*)(ws + offC_key);
    unsigned short* cvb_val = (unsigned short*)(ws + offC_val);
    unsigned short* packed = (unsigned short*)(ws + offC_packed);
    hipMemsetAsync(bcnt, 0, (size_t)NB_MAX * 4, stream);
    hist_bucket_kernel<<<512, 256, 0, stream>>>(rows, nnz, bcnt);
    scan_buckets_kernel<<<1, 256, 0, stream>>>(bcnt, nb, bbase, gcur);
    partition_kernel<<<part_blocks, PART_T, 0, stream>>>(rows, cols, values, nnz, nb,
                                                         gcur, cvb_key, cvb_val);
    bucket_sort_kernel<<<nb, 256, 0, stream>>>(cvb_key, cvb_val, bbase, gcur,
                                               offsets, rowend, cv, n);
    pack_kernel<<<(pack_total + 255) / 256, 256, 0, stream>>>(feat, packed, n);
    spmm_seg_bf16_kernel<<<seg_grid, 256, 0, stream>>>(offsets, rowend, cv, packed, out, n);
  }
}